// Round 10
// baseline (178.999 us; speedup 1.0000x reference)
//
#include <hip/hip_runtime.h>
#include <math.h>

// Z = Q_F (D * (Q_F^T X Q_S)) Q_S^T  ==  per-column solve (I - g*lam_j*G) y_j = (X Q_S)_j ; Z = Y Q_S^T
// (I - aG)^-1 = prod_{j=0..4} (I + a^(2^j) G^(2^j))  (exact 31-term Neumann sum; rho <= 0.76)
// GEMMs: bf16 MFMA, A = hi+lo split (2 products), B = bf16 (2^-9 rel, OK vs 0.099 threshold).
//
// R10: pack-Qs round. Evidence: every gemm reads Qs at 0.85-1.2 TB/s (FETCH/dur) while
// contiguous streams hit 6.3-6.5 TB/s; HBM activate/tFAW math puts 256-B-run scattered
// reads at ~1.1 TB/s -- matches. R9's per-step reorder didn't change the address stream;
// this round changes the layout: pack_kernel converts Qs ONCE into pre-swizzled bf16
// MFMA planes in BOTH orientations (QT for gemm1: plane[n][k]=Qs[k][n]; QN for gemm2:
// plane[n][k]=Qs[n][k]), reading Qs in 1-KB row-runs and writing 64 MB linearly.
// Both gemms then load B as LINEAR 8-KB plane reads (32 KB contiguous per block,
// L3-hot), LDS-verbatim (pre-swizzled-global pattern), zero conversion VALU.
// Also known: the harness's 268-MB poison fill (~41 us) is inside the timed iteration.
// Dispatches: pack -> gemm1(+prep) -> reduce1 -> solve -> gemm2 -> reduce2z.

typedef short short8 __attribute__((ext_vector_type(8)));
typedef float floatx16 __attribute__((ext_vector_type(16)));

#define KSPLIT 16
#define KCHUNK 256  // 4096 / KSPLIT, 4 steps of 64
constexpr int Mdim = 64;
constexpr int Ndim = 4096;
constexpr int TILE = Mdim * Ndim;  // 262144 floats = 1 MB

__device__ inline ushort f2bf(float f) {
    uint u = __float_as_uint(f);
    u += 0x7fff + ((u >> 16) & 1);  // RNE
    return (ushort)(u >> 16);
}
__device__ inline float bf2f(ushort h) { return __uint_as_float(((uint)h) << 16); }

__device__ inline floatx16 mfma_bf16(short8 a, short8 b, floatx16 c) {
    return __builtin_amdgcn_mfma_f32_32x32x16_bf16(a, b, c, 0, 0, 0);
}

// LDS plane layout (bf16, 64x64 tile): elem (r,k) at r*64 + ((k>>3)^(r&7))*8 + (k&7).
union SharedG1 {
    struct { ushort Ah[4096], Al[4096], Bh[4096]; } g;     // gemm1 (24 KB)
    struct { ushort planes[2][4096]; float red[256]; } p;  // prep (17 KB)
};

// Workgroup barrier WITHOUT vmcnt drain: LDS visibility only needs lgkmcnt(0).
__device__ inline void barrier_nodrain() {
    asm volatile("s_waitcnt lgkmcnt(0)" ::: "memory");
    __builtin_amdgcn_s_barrier();
    __builtin_amdgcn_sched_barrier(0);
}

// ---------------- pack: Qs -> QT (gemm1 planes) + QN (gemm2 planes) ---------
// Block (bt, cq): reads Qs rows [64bt,64bt+64) x cols [256cq,256cq+256) in 1-KB
// row-runs, emits 4 complete QN planes (nt=bt, kt=4cq+i) and 4 complete QT planes
// (nt=4cq+i, kt=bt). Plane index layout: Q*[nt*64 + kt] -> each gemm block's 4
// step-planes are 32 KB contiguous. Writes are full 16-B pieces, planes fully
// owned by one block (no partial lines).
__global__ __launch_bounds__(256, 4) void pack_kernel(const float* __restrict__ Qs,
                                                      ushort* __restrict__ QN,
                                                      ushort* __restrict__ QT) {
    __shared__ ushort Ls[64][264];
    const int b = blockIdx.x;  // 1024
    const int bt = b >> 4;     // Qs row-band 0..63
    const int cq = b & 15;     // 1-KB col chunk 0..15
    const int t = threadIdx.x;
    const int r = t >> 2, j = t & 3;
    const float* src = Qs + (size_t)(64 * bt + r) * 4096 + 256 * cq;
#pragma unroll
    for (int it = 0; it < 16; ++it) {
        float4 v = *(const float4*)&src[16 * it + 4 * j];
        ushort4 h;
        h.x = f2bf(v.x); h.y = f2bf(v.y); h.z = f2bf(v.z); h.w = f2bf(v.w);
        *(ushort4*)&Ls[r][16 * it + 4 * j] = h;
    }
    __syncthreads();
    const int n = t >> 2;
    // QN planes (row = Qs row): 16-B LDS moves, swizzle applied on the write
#pragma unroll
    for (int i = 0; i < 4; ++i) {
        ushort* pl = QN + ((size_t)bt * 64 + 4 * cq + i) * 4096;
#pragma unroll
        for (int gg = 0; gg < 2; ++gg) {
            int g = 2 * (t & 3) + gg;
            uint4 v = *(const uint4*)&Ls[n][64 * i + 8 * g];
            *(uint4*)&pl[n * 64 + ((g ^ (n & 7)) * 8)] = v;
        }
    }
    // QT planes (row = Qs col): u16 column gathers from Ls
#pragma unroll
    for (int i = 0; i < 4; ++i) {
        ushort* pl = QT + ((size_t)(4 * cq + i) * 64 + bt) * 4096;
#pragma unroll
        for (int gg = 0; gg < 2; ++gg) {
            int g = 2 * (t & 3) + gg;
            short8 w;
#pragma unroll
            for (int u = 0; u < 8; ++u) w[u] = (short)Ls[8 * g + u][64 * i + n];
            *(short8*)&pl[n * 64 + ((g ^ (n & 7)) * 8)] = w;
        }
    }
}

// ---------------- prep body: G, G^2, G^4, G^8, G^16 (one block) -------------
__device__ void prep_body(SharedG1& sh, const float* __restrict__ F, float* __restrict__ Gout) {
    const int t = threadIdx.x;
    const int l = t & 63, w = t >> 6;
    const int tm = w & 1, tn = w >> 1;
    const int am = tm * 32 + (l & 31);
    const int bn = tn * 32 + (l & 31);
    const int lk = l >> 5;
    ushort* Ph = sh.p.planes[0];
    ushort* Pl = sh.p.planes[1];
    float* red = sh.p.red;

    {  // load F rows from global, scatter transposed into planes: P[c][k] = F[k][c]
        const int r = t >> 2, c0 = (t & 3) * 16;
#pragma unroll
        for (int q = 0; q < 4; ++q) {
            float4 v = *(const float4*)&F[r * 64 + c0 + 4 * q];
            float fa[4] = {v.x, v.y, v.z, v.w};
#pragma unroll
            for (int i = 0; i < 4; ++i) {
                int c = c0 + 4 * q + i;
                ushort h = f2bf(fa[i]);
                int idx = c * 64 + (((r >> 3) ^ (c & 7)) * 8) + (r & 7);
                Ph[idx] = h;
                Pl[idx] = f2bf(fa[i] - bf2f(h));
            }
        }
    }
    barrier_nodrain();
    floatx16 acc;
    for (int i = 0; i < 16; ++i) acc[i] = 0.f;
    for (int s16 = 0; s16 < 4; ++s16) {
        int gk = 2 * s16 + lk;
        int ai = am * 64 + ((gk ^ (am & 7)) * 8);
        int bi = bn * 64 + ((gk ^ (bn & 7)) * 8);
        short8 ah = *(const short8*)&Ph[ai];
        short8 al = *(const short8*)&Pl[ai];
        short8 bh = *(const short8*)&Ph[bi];
        short8 bl = *(const short8*)&Pl[bi];
        acc = mfma_bf16(ah, bh, acc);
        acc = mfma_bf16(al, bh, acc);
        acc = mfma_bf16(ah, bl, acc);
    }
    float ss = 0.f;
    for (int r = 0; r < 16; ++r) ss += acc[r] * acc[r];
    red[t] = ss;
    barrier_nodrain();
    for (int off = 128; off > 0; off >>= 1) {
        if (t < off) red[t] += red[t + off];
        barrier_nodrain();
    }
    const float inv = 1.0f / (sqrtf(red[0]) + 1e-12f);
    for (int r = 0; r < 16; ++r) {
        int row = (r & 3) + 8 * (r >> 2) + 4 * lk + tm * 32;
        int col = tn * 32 + (l & 31);
        float v = acc[r] * inv;
        Gout[row * 64 + col] = v;
        ushort h = f2bf(v);
        int idx = row * 64 + (((col >> 3) ^ (row & 7)) * 8 + (col & 7));
        Ph[idx] = h;
        Pl[idx] = f2bf(v - bf2f(h));
    }
    for (int j = 1; j < 5; ++j) {
        barrier_nodrain();
        floatx16 a2;
        for (int i = 0; i < 16; ++i) a2[i] = 0.f;
        for (int s16 = 0; s16 < 4; ++s16) {
            int gk = 2 * s16 + lk;
            int ai = am * 64 + ((gk ^ (am & 7)) * 8);
            int bi = bn * 64 + ((gk ^ (bn & 7)) * 8);
            short8 ah = *(const short8*)&Ph[ai];
            short8 al = *(const short8*)&Pl[ai];
            short8 bh = *(const short8*)&Ph[bi];
            short8 bl = *(const short8*)&Pl[bi];
            a2 = mfma_bf16(ah, bh, a2);
            a2 = mfma_bf16(al, bh, a2);
            a2 = mfma_bf16(ah, bl, a2);
        }
        barrier_nodrain();
        for (int r = 0; r < 16; ++r) {
            int row = (r & 3) + 8 * (r >> 2) + 4 * lk + tm * 32;
            int col = tn * 32 + (l & 31);
            float v = a2[r];
            Gout[j * 4096 + row * 64 + col] = v;
            ushort h = f2bf(v);
            int idx = row * 64 + (((col >> 3) ^ (row & 7)) * 8 + (col & 7));
            Ph[idx] = h;
            Pl[idx] = f2bf(v - bf2f(h));
        }
    }
}

// ---------------- gemm1: P1[ks] tile(nt) = X-chunk @ Qs-chunk (+ prep) ------
// B = pre-swizzled QT planes, loaded LINEARLY (16 B/thread x2) and written
// LDS-verbatim; depth-1 next-plane register prefetch (QT is L3-hot).
// A f32 (L2-hot) staged hi/lo as before. Two nodrain barriers per step.
// Tile-contiguous fragment-order store.
__global__ __launch_bounds__(256, 4) void gemm1_kernel(const float* __restrict__ A,
                                                       const ushort* __restrict__ QT,
                                                       float* __restrict__ C,
                                                       const float* __restrict__ F,
                                                       float* __restrict__ Gp) {
    __shared__ SharedG1 sh;
    const int bid = blockIdx.x;
    if (bid == 0) { prep_body(sh, F, Gp); return; }
    const int b = bid - 1;
    const int nt = b & 63;
    const int ks = b >> 6;
    const int kb = ks * KCHUNK;
    const int t = threadIdx.x;
    const int l = t & 63, w = t >> 6;
    const int tm = w & 1, tn = w >> 1;
    const int am = tm * 32 + (l & 31);
    const int bn = tn * 32 + (l & 31);
    const int lk = l >> 5;
    const int sr = t >> 2, sj = t & 3;  // A row-staging map

    floatx16 acc;
    for (int i = 0; i < 16; ++i) acc[i] = 0.f;

    const ushort* qtb = QT + ((size_t)nt * 64 + 4 * ks) * 4096;  // 4 planes, 32 KB contiguous
    uint4 bc0 = *(const uint4*)&qtb[(size_t)t * 8];
    uint4 bc1 = *(const uint4*)&qtb[2048 + (size_t)t * 8];

#pragma unroll
    for (int step = 0; step < KCHUNK / 64; ++step) {
        const int k0 = kb + step * 64;
        // A loads for this step (L2-hot, short latency)
        float4 av[4];
#pragma unroll
        for (int s = 0; s < 4; ++s)
            av[s] = *(const float4*)&A[sr * 4096 + k0 + 4 * sj + 16 * s];
        // prefetch next B plane (L3-hot)
        uint4 bn0, bn1;
        if (step + 1 < KCHUNK / 64) {
            bn0 = *(const uint4*)&qtb[(size_t)(step + 1) * 4096 + t * 8];
            bn1 = *(const uint4*)&qtb[(size_t)(step + 1) * 4096 + 2048 + t * 8];
        }
        barrier_nodrain();  // previous step's frag ds_reads done (lgkm only)
        // B plane -> LDS verbatim (pre-swizzled in global)
        *(uint4*)&sh.g.Bh[t * 8] = bc0;
        *(uint4*)&sh.g.Bh[2048 + t * 8] = bc1;
        // stage A (hi + lo)
#pragma unroll
        for (int s = 0; s < 4; ++s) {
            int off = 4 * sj + 16 * s;
            int idx = sr * 64 + (((off >> 3) ^ (sr & 7)) * 8 + (off & 7));
            float fa[4] = {av[s].x, av[s].y, av[s].z, av[s].w};
            ushort4 h4, l4;
            ushort* hp = (ushort*)&h4; ushort* lp = (ushort*)&l4;
#pragma unroll
            for (int i = 0; i < 4; ++i) {
                ushort h = f2bf(fa[i]);
                hp[i] = h; lp[i] = f2bf(fa[i] - bf2f(h));
            }
            *(ushort4*)&sh.g.Ah[idx] = h4;
            *(ushort4*)&sh.g.Al[idx] = l4;
        }
        barrier_nodrain();  // staged planes visible to all waves
#pragma unroll
        for (int s16 = 0; s16 < 4; ++s16) {
            int gk = 2 * s16 + lk;
            int ai = am * 64 + ((gk ^ (am & 7)) * 8);
            int bi = bn * 64 + ((gk ^ (bn & 7)) * 8);
            short8 ah = *(const short8*)&sh.g.Ah[ai];
            short8 al = *(const short8*)&sh.g.Al[ai];
            short8 bh = *(const short8*)&sh.g.Bh[bi];
            acc = mfma_bf16(ah, bh, acc);
            acc = mfma_bf16(al, bh, acc);
        }
        bc0 = bn0; bc1 = bn1;
    }
    // tile-contiguous fragment-order store: float idx = w*1024 + r*64 + l
    float* Cp = C + (size_t)ks * TILE + nt * 4096;
    const int base = w * 1024 + l;
#pragma unroll
    for (int r = 0; r < 16; ++r) Cp[base + r * 64] = acc[r];
}

// ---------------- reduce1: W = sum of KSPLIT P1 slabs (flat, coalesced) -----
__global__ __launch_bounds__(256) void reduce_kernel(const float* __restrict__ P,
                                                     float* __restrict__ out) {
    const int i = blockIdx.x * 256 + threadIdx.x;  // float4 index, 65536 total
    float4 a = {0.f, 0.f, 0.f, 0.f};
#pragma unroll
    for (int s = 0; s < KSPLIT; ++s) {
        const float4 v = *(const float4*)&P[(size_t)s * TILE + 4 * i];
        a.x += v.x; a.y += v.y; a.z += v.z; a.w += v.w;
    }
    *(float4*)&out[4 * i] = a;
}

// ---------------- solve: T from W (tile-order gather); Neumann; emit Ybf ----
// 256 blocks x 16 columns. W is 1 MB L2/L3-hot -> gather is cheap.
// Ybf layout [R4-verified]: elem (r, col) at (col>>3)*512 + r*8 + (col&7).
__global__ __launch_bounds__(256) void solve_kernel(const float* __restrict__ W,
                                                    const float* __restrict__ Gp,
                                                    const float* __restrict__ lam,
                                                    const float* __restrict__ gammap,
                                                    ushort* __restrict__ Yh,
                                                    ushort* __restrict__ Yl) {
    __shared__ float Gs[64][68];
    __shared__ float T[64][17];
    const int t = threadIdx.x;
    const int c0 = blockIdx.x * 16;
    const int nt = blockIdx.x >> 2;
    for (int e = t; e < 1024; e += 256) {
        const int row = e >> 4, cc = e & 15;
        const int cit = (blockIdx.x & 3) * 16 + cc;  // col within tile
        const int rr = (row & 3) | (((row >> 3) & 3) << 2);
        const int lk = (row >> 2) & 1;
        const int ww = (row >> 5) + 2 * (cit >> 5);
        const int ll = (cit & 31) + 32 * lk;
        T[row][cc] = W[nt * 4096 + ww * 1024 + rr * 64 + ll];
    }
    const int tx = t & 15;
    const int r4 = (t >> 4) * 4;
    const float a0 = gammap[0] * lam[c0 + tx];
    float s = a0;
    for (int j = 0; j < 5; ++j) {
        __syncthreads();
        for (int e = t; e < 4096; e += 256) Gs[e >> 6][e & 63] = Gp[j * 4096 + e];
        __syncthreads();
        float u0 = 0.f, u1 = 0.f, u2 = 0.f, u3 = 0.f;
#pragma unroll 8
        for (int k = 0; k < 64; ++k) {
            const float tv = T[k][tx];
            const float4 g = *(const float4*)&Gs[k][r4];
            u0 += g.x * tv; u1 += g.y * tv; u2 += g.z * tv; u3 += g.w * tv;
        }
        __syncthreads();
        T[r4 + 0][tx] += s * u0;
        T[r4 + 1][tx] += s * u1;
        T[r4 + 2][tx] += s * u2;
        T[r4 + 3][tx] += s * u3;
        s = s * s;
    }
    __syncthreads();
    for (int e = t; e < 1024; e += 256) {
        const int r = e >> 4, cc = e & 15, col = c0 + cc;
        const float v = T[r][cc];
        const ushort h = f2bf(v);
        const int idx = (col >> 3) * 512 + r * 8 + (col & 7);
        Yh[idx] = h;
        Yl[idx] = f2bf(v - bf2f(h));
    }
}

// ---------------- gemm2: P2[ks] tile(nt) = Ybf-chunk @ Qs^T-chunk -----------
// A-frags register-direct from Ybf planes; B = pre-swizzled QN planes loaded
// LINEARLY, LDS dbuf verbatim; ONE nodrain barrier/step; depth-1 B prefetch;
// tile-contiguous store.
__global__ __launch_bounds__(256, 4) void gemm2_kernel(const ushort* __restrict__ Yh,
                                                       const ushort* __restrict__ Yl,
                                                       const ushort* __restrict__ QN,
                                                       float* __restrict__ C) {
    __shared__ ushort Bhs[2][4096];
    const int b = blockIdx.x;
    const int nt = b & 63;
    const int ks = b >> 6;
    const int kb = ks * KCHUNK;
    const int t = threadIdx.x;
    const int l = t & 63, w = t >> 6;
    const int tm = w & 1, tn = w >> 1;
    const int am = tm * 32 + (l & 31);
    const int bn = tn * 32 + (l & 31);
    const int lk = l >> 5;

    floatx16 acc;
    for (int i = 0; i < 16; ++i) acc[i] = 0.f;

    const ushort* qnb = QN + ((size_t)nt * 64 + 4 * ks) * 4096;  // 4 planes, 32 KB contiguous
    uint4 bc0 = *(const uint4*)&qnb[(size_t)t * 8];
    uint4 bc1 = *(const uint4*)&qnb[2048 + (size_t)t * 8];

#pragma unroll
    for (int step = 0; step < KCHUNK / 64; ++step) {
        const int k0 = kb + step * 64;
        const int par = step & 1;
        // prefetch next B plane (L3-hot)
        uint4 bn0, bn1;
        if (step + 1 < KCHUNK / 64) {
            bn0 = *(const uint4*)&qnb[(size_t)(step + 1) * 4096 + t * 8];
            bn1 = *(const uint4*)&qnb[(size_t)(step + 1) * 4096 + 2048 + t * 8];
        }
        // A frags direct from Ybf planes (L2/L3-hot, 16B coalesced)
        short8 afh[4], afl[4];
#pragma unroll
        for (int s16 = 0; s16 < 4; ++s16) {
            int gk = (k0 >> 3) + 2 * s16 + lk;
            afh[s16] = *(const short8*)&Yh[gk * 512 + am * 8];
            afl[s16] = *(const short8*)&Yl[gk * 512 + am * 8];
        }
        // B plane -> LDS dbuf verbatim
        *(uint4*)&Bhs[par][t * 8] = bc0;
        *(uint4*)&Bhs[par][2048 + t * 8] = bc1;
        barrier_nodrain();  // this half's writes visible; prev-half reads drained (lgkm)
#pragma unroll
        for (int s16 = 0; s16 < 4; ++s16) {
            int gk = 2 * s16 + lk;
            int bi = bn * 64 + ((gk ^ (bn & 7)) * 8);
            short8 bh = *(const short8*)&Bhs[par][bi];
            acc = mfma_bf16(afh[s16], bh, acc);
            acc = mfma_bf16(afl[s16], bh, acc);
        }
        bc0 = bn0; bc1 = bn1;
    }
    // tile-contiguous fragment-order store
    float* Cp = C + (size_t)ks * TILE + nt * 4096;
    const int base = w * 1024 + l;
#pragma unroll
    for (int r = 0; r < 16; ++r) Cp[base + r * 64] = acc[r];
}

// ---------------- reduce2z: Z(row-major) = sum of P2 slabs (tile-order) -----
// 256 blocks: nt = bid&63, row-quarter q = bid>>6 (rows q*16..q*16+15).
__global__ __launch_bounds__(256) void reduce2z_kernel(const float* __restrict__ P,
                                                       float* __restrict__ Z) {
    __shared__ float a4[2][8][64];  // [tn][rr][l]
    const int bid = blockIdx.x;
    const int nt = bid & 63;
    const int q = bid >> 6;
    const int tm = q >> 1;
    const int rbase = (q & 1) * 8;
    const int t = threadIdx.x;
    // coalesced slab reads: thread (tn, rr, lq) sums 16 slabs for 4 floats
    const int tn = t >> 7, rr = (t >> 4) & 7, lq = t & 15;
    const size_t off = (size_t)nt * 4096 + (tm + 2 * tn) * 1024 + (rbase + rr) * 64 + 4 * lq;
    float4 a = {0.f, 0.f, 0.f, 0.f};
#pragma unroll
    for (int s = 0; s < KSPLIT; ++s) {
        const float4 v = *(const float4*)&P[(size_t)s * TILE + off];
        a.x += v.x; a.y += v.y; a.z += v.z; a.w += v.w;
    }
    *(float4*)&a4[tn][rr][4 * lq] = a;
    __syncthreads();
    // write row-major: thread -> (orow, 4-col quad)
    const int orow = q * 16 + (t >> 4);
    const int cquad = t & 15;
    const int lk = (orow >> 2) & 1;
    const int rr2 = ((orow & 3) | (((orow >> 3) & 3) << 2)) - rbase;  // in [0,8)
    float4 o;
    float* op = (float*)&o;
#pragma unroll
    for (int v = 0; v < 4; ++v) {
        const int col = 4 * cquad + v;
        op[v] = a4[col >> 5][rr2][(col & 31) + 32 * lk];
    }
    *(float4*)&Z[(size_t)orow * 4096 + nt * 64 + 4 * cquad] = o;
}

extern "C" void kernel_launch(void* const* d_in, const int* in_sizes, int n_in,
                              void* d_out, int out_size, void* d_ws, size_t ws_size,
                              hipStream_t stream) {
    const float* X     = (const float*)d_in[0];
    const float* F     = (const float*)d_in[1];
    const float* Qs    = (const float*)d_in[2];
    const float* lam   = (const float*)d_in[3];
    const float* gamma = (const float*)d_in[4];
    float* Z = (float*)d_out;

    float* P1 = (float*)d_ws;                    // 16 MB partial slabs (gemm1)
    float* P2 = P1 + (size_t)KSPLIT * TILE;      // 16 MB partial slabs (gemm2)
    float* W  = P2 + (size_t)KSPLIT * TILE;      // 1 MB reduced W (tile order)
    float* Gp = W + TILE;                        // 80 KB: G, G^2, G^4, G^8, G^16
    ushort* Yh = (ushort*)(Gp + 5 * 4096);       // 512 KB Y hi plane (fragment layout)
    ushort* Yl = Yh + TILE;                      // 512 KB Y lo plane
    ushort* QT = Yl + TILE;                      // 32 MB packed Qs^T planes (gemm1 B)
    ushort* QN = QT + (size_t)64 * 64 * 4096;    // 32 MB packed Qs planes (gemm2 B)

    pack_kernel<<<1024, 256, 0, stream>>>(Qs, QN, QT);
    gemm1_kernel<<<64 * KSPLIT + 1, 256, 0, stream>>>(X, QT, P1, F, Gp);
    reduce_kernel<<<256, 256, 0, stream>>>(P1, W);
    solve_kernel<<<Ndim / 16, 256, 0, stream>>>(W, Gp, lam, gamma, Yh, Yl);
    gemm2_kernel<<<64 * KSPLIT, 256, 0, stream>>>(Yh, Yl, QN, P2);
    reduce2z_kernel<<<256, 256, 0, stream>>>(P2, Z);
}

// Round 11
// 166.523 us; speedup vs baseline: 1.0749x; 1.0749x over previous
//
#include <hip/hip_runtime.h>
#include <math.h>

// Z = Q_F (D * (Q_F^T X Q_S)) Q_S^T  ==  per-column solve (I - g*lam_j*G) y_j = (X Q_S)_j ; Z = Y Q_S^T
// (I - aG)^-1 = prod_{j=0..4} (I + a^(2^j) G^(2^j))  (exact 31-term Neumann sum; rho <= 0.76)
// GEMMs: bf16 MFMA, A = hi+lo split (2 products), B = bf16 (2^-9 rel, OK vs 0.099 threshold).
//
// R11: byte-halving round. R9/R10 evidence: gemm read service rate is ~1.2 TB/s regardless
// of address pattern (linear pre-swizzled planes didn't beat strided staging) -> the only
// gemm lever left is FEWER BYTES. R10's dual-orientation pack gained ~20 us on the gemms
// but cost ~25 us (column-gather writes). This round: pack Qs -> bf16 ROW-MAJOR only
// (pure grid-stride convert, 64 MB linear read + 32 MB linear write ~ 15 us); both gemms
// stage B from Qbf with HALF the HBM bytes and byte-identical values (f2bf moved from
// staging to pack). gemm2 staging becomes plane-verbatim 16-B LDS writes (zero cvt VALU).
// Fixed harness overhead inside dur_us: ~79 us (R4: 409 total vs 330 kernel).
// Dispatches: packq -> gemm1(+prep) -> reduce1 -> solve -> gemm2 -> reduce2z.

typedef short short8 __attribute__((ext_vector_type(8)));
typedef float floatx16 __attribute__((ext_vector_type(16)));

#define KSPLIT 16
#define KCHUNK 256  // 4096 / KSPLIT, 4 steps of 64
constexpr int Mdim = 64;
constexpr int Ndim = 4096;
constexpr int TILE = Mdim * Ndim;  // 262144 floats = 1 MB

__device__ inline ushort f2bf(float f) {
    uint u = __float_as_uint(f);
    u += 0x7fff + ((u >> 16) & 1);  // RNE
    return (ushort)(u >> 16);
}
__device__ inline float bf2f(ushort h) { return __uint_as_float(((uint)h) << 16); }

__device__ inline floatx16 mfma_bf16(short8 a, short8 b, floatx16 c) {
    return __builtin_amdgcn_mfma_f32_32x32x16_bf16(a, b, c, 0, 0, 0);
}

// LDS plane layout (bf16, 64x64 tile): elem (r,k) at r*64 + ((k>>3)^(r&7))*8 + (k&7).
union SharedG1 {
    struct { ushort Ah[4096], Al[4096], Bh[4096]; } g;     // gemm1 (24 KB)
    struct { ushort planes[2][4096]; float red[256]; } p;  // prep (17 KB)
};

// Workgroup barrier WITHOUT vmcnt drain: LDS visibility only needs lgkmcnt(0).
__device__ inline void barrier_nodrain() {
    asm volatile("s_waitcnt lgkmcnt(0)" ::: "memory");
    __builtin_amdgcn_s_barrier();
    __builtin_amdgcn_sched_barrier(0);
}

// ---------------- packq: Qbf = bf16(Qs), row-major, fully linear ------------
// 2048 blocks x 256 threads x 8 float4: lane-consecutive 1-KB wave runs.
__global__ __launch_bounds__(256) void packq_kernel(const float* __restrict__ Qs,
                                                    ushort* __restrict__ Qbf) {
    const size_t base = (size_t)blockIdx.x * 2048 + threadIdx.x;  // float4 units
#pragma unroll
    for (int u = 0; u < 8; ++u) {
        const float4 v = ((const float4*)Qs)[base + 256 * u];
        ushort4 h;
        h.x = f2bf(v.x); h.y = f2bf(v.y); h.z = f2bf(v.z); h.w = f2bf(v.w);
        ((ushort4*)Qbf)[base + 256 * u] = h;
    }
}

// ---------------- prep body: G, G^2, G^4, G^8, G^16 (one block) -------------
__device__ void prep_body(SharedG1& sh, const float* __restrict__ F, float* __restrict__ Gout) {
    const int t = threadIdx.x;
    const int l = t & 63, w = t >> 6;
    const int tm = w & 1, tn = w >> 1;
    const int am = tm * 32 + (l & 31);
    const int bn = tn * 32 + (l & 31);
    const int lk = l >> 5;
    ushort* Ph = sh.p.planes[0];
    ushort* Pl = sh.p.planes[1];
    float* red = sh.p.red;

    {  // load F rows from global, scatter transposed into planes: P[c][k] = F[k][c]
        const int r = t >> 2, c0 = (t & 3) * 16;
#pragma unroll
        for (int q = 0; q < 4; ++q) {
            float4 v = *(const float4*)&F[r * 64 + c0 + 4 * q];
            float fa[4] = {v.x, v.y, v.z, v.w};
#pragma unroll
            for (int i = 0; i < 4; ++i) {
                int c = c0 + 4 * q + i;
                ushort h = f2bf(fa[i]);
                int idx = c * 64 + (((r >> 3) ^ (c & 7)) * 8) + (r & 7);
                Ph[idx] = h;
                Pl[idx] = f2bf(fa[i] - bf2f(h));
            }
        }
    }
    barrier_nodrain();
    floatx16 acc;
    for (int i = 0; i < 16; ++i) acc[i] = 0.f;
    for (int s16 = 0; s16 < 4; ++s16) {
        int gk = 2 * s16 + lk;
        int ai = am * 64 + ((gk ^ (am & 7)) * 8);
        int bi = bn * 64 + ((gk ^ (bn & 7)) * 8);
        short8 ah = *(const short8*)&Ph[ai];
        short8 al = *(const short8*)&Pl[ai];
        short8 bh = *(const short8*)&Ph[bi];
        short8 bl = *(const short8*)&Pl[bi];
        acc = mfma_bf16(ah, bh, acc);
        acc = mfma_bf16(al, bh, acc);
        acc = mfma_bf16(ah, bl, acc);
    }
    float ss = 0.f;
    for (int r = 0; r < 16; ++r) ss += acc[r] * acc[r];
    red[t] = ss;
    barrier_nodrain();
    for (int off = 128; off > 0; off >>= 1) {
        if (t < off) red[t] += red[t + off];
        barrier_nodrain();
    }
    const float inv = 1.0f / (sqrtf(red[0]) + 1e-12f);
    for (int r = 0; r < 16; ++r) {
        int row = (r & 3) + 8 * (r >> 2) + 4 * lk + tm * 32;
        int col = tn * 32 + (l & 31);
        float v = acc[r] * inv;
        Gout[row * 64 + col] = v;
        ushort h = f2bf(v);
        int idx = row * 64 + (((col >> 3) ^ (row & 7)) * 8 + (col & 7));
        Ph[idx] = h;
        Pl[idx] = f2bf(v - bf2f(h));
    }
    for (int j = 1; j < 5; ++j) {
        barrier_nodrain();
        floatx16 a2;
        for (int i = 0; i < 16; ++i) a2[i] = 0.f;
        for (int s16 = 0; s16 < 4; ++s16) {
            int gk = 2 * s16 + lk;
            int ai = am * 64 + ((gk ^ (am & 7)) * 8);
            int bi = bn * 64 + ((gk ^ (bn & 7)) * 8);
            short8 ah = *(const short8*)&Ph[ai];
            short8 al = *(const short8*)&Pl[ai];
            short8 bh = *(const short8*)&Ph[bi];
            short8 bl = *(const short8*)&Pl[bi];
            a2 = mfma_bf16(ah, bh, a2);
            a2 = mfma_bf16(al, bh, a2);
            a2 = mfma_bf16(ah, bl, a2);
        }
        barrier_nodrain();
        for (int r = 0; r < 16; ++r) {
            int row = (r & 3) + 8 * (r >> 2) + 4 * lk + tm * 32;
            int col = tn * 32 + (l & 31);
            float v = a2[r];
            Gout[j * 4096 + row * 64 + col] = v;
            ushort h = f2bf(v);
            int idx = row * 64 + (((col >> 3) ^ (row & 7)) * 8 + (col & 7));
            Ph[idx] = h;
            Pl[idx] = f2bf(v - bf2f(h));
        }
    }
}

// gemm1 B-panel load for one 64-k step: rows kr2(+1)(+32)(+33), 4 cols each (8 B).
__device__ inline void load_b1(ushort4 (&dst)[4], const ushort* __restrict__ Qbf,
                               int n0, int kk, int nq, int kr2) {
    dst[0] = *(const ushort4*)&Qbf[(size_t)(kk + kr2) * 4096 + n0 + 4 * nq];
    dst[1] = *(const ushort4*)&Qbf[(size_t)(kk + kr2 + 1) * 4096 + n0 + 4 * nq];
    dst[2] = *(const ushort4*)&Qbf[(size_t)(kk + kr2 + 32) * 4096 + n0 + 4 * nq];
    dst[3] = *(const ushort4*)&Qbf[(size_t)(kk + kr2 + 33) * 4096 + n0 + 4 * nq];
}

// ---------------- gemm1: P1[ks] tile(nt) = X-chunk @ Qbf-chunk (+ prep) -----
// B from row-major bf16 Qbf (HALF the bytes of f32 Qs); depth-2 B register
// prefetch; A (L2-hot f32) staged hi/lo; two nodrain barriers/step;
// tile-contiguous fragment-order store.
__global__ __launch_bounds__(256, 4) void gemm1_kernel(const float* __restrict__ A,
                                                       const ushort* __restrict__ Qbf,
                                                       float* __restrict__ C,
                                                       const float* __restrict__ F,
                                                       float* __restrict__ Gp) {
    __shared__ SharedG1 sh;
    const int bid = blockIdx.x;
    if (bid == 0) { prep_body(sh, F, Gp); return; }
    const int b = bid - 1;
    const int nt = b & 63;
    const int n0 = nt * 64;
    const int ks = b >> 6;
    const int kb = ks * KCHUNK;
    const int t = threadIdx.x;
    const int l = t & 63, w = t >> 6;
    const int tm = w & 1, tn = w >> 1;
    const int am = tm * 32 + (l & 31);
    const int bn = tn * 32 + (l & 31);
    const int lk = l >> 5;
    const int sr = t >> 2, sj = t & 3;          // A row-staging map
    const int nq = t & 15, kr2 = 2 * (t >> 4);  // B transpose-staging map

    floatx16 acc;
    for (int i = 0; i < 16; ++i) acc[i] = 0.f;

    ushort4 bbuf[4][4];
    load_b1(bbuf[0], Qbf, n0, kb, nq, kr2);
    load_b1(bbuf[1], Qbf, n0, kb + 64, nq, kr2);

#pragma unroll
    for (int step = 0; step < KCHUNK / 64; ++step) {
        const int k0 = kb + step * 64;
        // A loads for this step (L2-hot, short latency)
        float4 av[4];
#pragma unroll
        for (int s = 0; s < 4; ++s)
            av[s] = *(const float4*)&A[sr * 4096 + k0 + 4 * sj + 16 * s];
        // prefetch B two steps ahead (HBM latency spans ~2 steps of staging+MFMA)
        if (step + 2 < KCHUNK / 64)
            load_b1(bbuf[step + 2], Qbf, n0, k0 + 128, nq, kr2);
        barrier_nodrain();  // previous step's frag ds_reads done (lgkm only; vmem in flight)
        // stage B (pre-converted bf16); counted vmcnt at first bbuf[step] use
#pragma unroll
        for (int s = 0; s < 2; ++s) {
            int k = kr2 + 32 * s;
            const ushort* ra = (const ushort*)&bbuf[step][2 * s];      // row k
            const ushort* rb = (const ushort*)&bbuf[step][2 * s + 1];  // row k+1
#pragma unroll
            for (int i = 0; i < 4; ++i) {
                int n = 4 * nq + i;
                int idx = n * 64 + (((k >> 3) ^ (n & 7)) * 8 + (k & 7));
                ushort2 hp2;
                hp2.x = ra[i];
                hp2.y = rb[i];
                *(ushort2*)&sh.g.Bh[idx] = hp2;
            }
        }
        // stage A (hi + lo)
#pragma unroll
        for (int s = 0; s < 4; ++s) {
            int off = 4 * sj + 16 * s;
            int idx = sr * 64 + (((off >> 3) ^ (sr & 7)) * 8 + (off & 7));
            float fa[4] = {av[s].x, av[s].y, av[s].z, av[s].w};
            ushort4 h4, l4;
            ushort* hp = (ushort*)&h4; ushort* lp = (ushort*)&l4;
#pragma unroll
            for (int i = 0; i < 4; ++i) {
                ushort h = f2bf(fa[i]);
                hp[i] = h; lp[i] = f2bf(fa[i] - bf2f(h));
            }
            *(ushort4*)&sh.g.Ah[idx] = h4;
            *(ushort4*)&sh.g.Al[idx] = l4;
        }
        barrier_nodrain();  // staged planes visible to all waves
#pragma unroll
        for (int s16 = 0; s16 < 4; ++s16) {
            int gk = 2 * s16 + lk;
            int ai = am * 64 + ((gk ^ (am & 7)) * 8);
            int bi = bn * 64 + ((gk ^ (bn & 7)) * 8);
            short8 ah = *(const short8*)&sh.g.Ah[ai];
            short8 al = *(const short8*)&sh.g.Al[ai];
            short8 bh = *(const short8*)&sh.g.Bh[bi];
            acc = mfma_bf16(ah, bh, acc);
            acc = mfma_bf16(al, bh, acc);
        }
    }
    // tile-contiguous fragment-order store: float idx = w*1024 + r*64 + l
    float* Cp = C + (size_t)ks * TILE + nt * 4096;
    const int base = w * 1024 + l;
#pragma unroll
    for (int r = 0; r < 16; ++r) Cp[base + r * 64] = acc[r];
}

// ---------------- reduce1: W = sum of KSPLIT P1 slabs (flat, coalesced) -----
__global__ __launch_bounds__(256) void reduce_kernel(const float* __restrict__ P,
                                                     float* __restrict__ out) {
    const int i = blockIdx.x * 256 + threadIdx.x;  // float4 index, 65536 total
    float4 a = {0.f, 0.f, 0.f, 0.f};
#pragma unroll
    for (int s = 0; s < KSPLIT; ++s) {
        const float4 v = *(const float4*)&P[(size_t)s * TILE + 4 * i];
        a.x += v.x; a.y += v.y; a.z += v.z; a.w += v.w;
    }
    *(float4*)&out[4 * i] = a;
}

// ---------------- solve: T from W (tile-order gather); Neumann; emit Ybf ----
// 256 blocks x 16 columns. W is 1 MB L2/L3-hot -> gather is cheap.
// Ybf layout [R4-verified]: elem (r, col) at (col>>3)*512 + r*8 + (col&7).
__global__ __launch_bounds__(256) void solve_kernel(const float* __restrict__ W,
                                                    const float* __restrict__ Gp,
                                                    const float* __restrict__ lam,
                                                    const float* __restrict__ gammap,
                                                    ushort* __restrict__ Yh,
                                                    ushort* __restrict__ Yl) {
    __shared__ float Gs[64][68];
    __shared__ float T[64][17];
    const int t = threadIdx.x;
    const int c0 = blockIdx.x * 16;
    const int nt = blockIdx.x >> 2;
    for (int e = t; e < 1024; e += 256) {
        const int row = e >> 4, cc = e & 15;
        const int cit = (blockIdx.x & 3) * 16 + cc;  // col within tile
        const int rr = (row & 3) | (((row >> 3) & 3) << 2);
        const int lk = (row >> 2) & 1;
        const int ww = (row >> 5) + 2 * (cit >> 5);
        const int ll = (cit & 31) + 32 * lk;
        T[row][cc] = W[nt * 4096 + ww * 1024 + rr * 64 + ll];
    }
    const int tx = t & 15;
    const int r4 = (t >> 4) * 4;
    const float a0 = gammap[0] * lam[c0 + tx];
    float s = a0;
    for (int j = 0; j < 5; ++j) {
        __syncthreads();
        for (int e = t; e < 4096; e += 256) Gs[e >> 6][e & 63] = Gp[j * 4096 + e];
        __syncthreads();
        float u0 = 0.f, u1 = 0.f, u2 = 0.f, u3 = 0.f;
#pragma unroll 8
        for (int k = 0; k < 64; ++k) {
            const float tv = T[k][tx];
            const float4 g = *(const float4*)&Gs[k][r4];
            u0 += g.x * tv; u1 += g.y * tv; u2 += g.z * tv; u3 += g.w * tv;
        }
        __syncthreads();
        T[r4 + 0][tx] += s * u0;
        T[r4 + 1][tx] += s * u1;
        T[r4 + 2][tx] += s * u2;
        T[r4 + 3][tx] += s * u3;
        s = s * s;
    }
    __syncthreads();
    for (int e = t; e < 1024; e += 256) {
        const int r = e >> 4, cc = e & 15, col = c0 + cc;
        const float v = T[r][cc];
        const ushort h = f2bf(v);
        const int idx = (col >> 3) * 512 + r * 8 + (col & 7);
        Yh[idx] = h;
        Yl[idx] = f2bf(v - bf2f(h));
    }
}

// ---------------- gemm2: P2[ks] tile(nt) = Ybf-chunk @ Qbf^T-chunk ----------
// A-frags register-direct from Ybf planes; B from row-major bf16 Qbf rows
// (n0..n0+63, 128 B per row per step -- HALF the bytes); full 4-step panel
// loaded up-front (8 uint4/thread); staging = plane-verbatim 16-B LDS writes
// (zero cvt VALU); ONE nodrain barrier/step; tile-contiguous store.
__global__ __launch_bounds__(256, 4) void gemm2_kernel(const ushort* __restrict__ Yh,
                                                       const ushort* __restrict__ Yl,
                                                       const ushort* __restrict__ Qbf,
                                                       float* __restrict__ C) {
    __shared__ ushort Bhs[2][4096];
    const int b = blockIdx.x;
    const int nt = b & 63;
    const int n0 = nt * 64;
    const int ks = b >> 6;
    const int kb = ks * KCHUNK;
    const int t = threadIdx.x;
    const int l = t & 63, w = t >> 6;
    const int tm = w & 1, tn = w >> 1;
    const int am = tm * 32 + (l & 31);
    const int bn = tn * 32 + (l & 31);
    const int lk = l >> 5;
    const int sr = t >> 2, sj = t & 3;  // B row-staging map

    floatx16 acc;
    for (int i = 0; i < 16; ++i) acc[i] = 0.f;

    // full-panel load: row n0+sr, cols kb..kb+255 (512 B per row, 32 B per thread)
    uint4 bbuf[4][2];
#pragma unroll
    for (int st = 0; st < 4; ++st) {
        const size_t ro = (size_t)(n0 + sr) * 4096 + kb + 64 * st + 16 * sj;
        bbuf[st][0] = *(const uint4*)&Qbf[ro];
        bbuf[st][1] = *(const uint4*)&Qbf[ro + 8];
    }

#pragma unroll
    for (int step = 0; step < KCHUNK / 64; ++step) {
        const int k0 = kb + step * 64;
        const int par = step & 1;
        // A frags direct from Ybf planes (L2/L3-hot, 16B coalesced)
        short8 afh[4], afl[4];
#pragma unroll
        for (int s16 = 0; s16 < 4; ++s16) {
            int gk = (k0 >> 3) + 2 * s16 + lk;
            afh[s16] = *(const short8*)&Yh[gk * 512 + am * 8];
            afl[s16] = *(const short8*)&Yl[gk * 512 + am * 8];
        }
        // stage B: plane-verbatim 16-B LDS writes (k&7 runs contiguous; swizzle on k>>3)
        {
            const int idx0 = sr * 64 + (((2 * sj + 0) ^ (sr & 7)) * 8);
            const int idx1 = sr * 64 + (((2 * sj + 1) ^ (sr & 7)) * 8);
            *(uint4*)&Bhs[par][idx0] = bbuf[step][0];
            *(uint4*)&Bhs[par][idx1] = bbuf[step][1];
        }
        barrier_nodrain();  // this half's writes visible; prev-half reads drained (lgkm)
#pragma unroll
        for (int s16 = 0; s16 < 4; ++s16) {
            int gk = 2 * s16 + lk;
            int bi = bn * 64 + ((gk ^ (bn & 7)) * 8);
            short8 bh = *(const short8*)&Bhs[par][bi];
            acc = mfma_bf16(afh[s16], bh, acc);
            acc = mfma_bf16(afl[s16], bh, acc);
        }
    }
    // tile-contiguous fragment-order store
    float* Cp = C + (size_t)ks * TILE + nt * 4096;
    const int base = w * 1024 + l;
#pragma unroll
    for (int r = 0; r < 16; ++r) Cp[base + r * 64] = acc[r];
}

// ---------------- reduce2z: Z(row-major) = sum of P2 slabs (tile-order) -----
// 256 blocks: nt = bid&63, row-quarter q = bid>>6 (rows q*16..q*16+15).
__global__ __launch_bounds__(256) void reduce2z_kernel(const float* __restrict__ P,
                                                       float* __restrict__ Z) {
    __shared__ float a4[2][8][64];  // [tn][rr][l]
    const int bid = blockIdx.x;
    const int nt = bid & 63;
    const int q = bid >> 6;
    const int tm = q >> 1;
    const int rbase = (q & 1) * 8;
    const int t = threadIdx.x;
    // coalesced slab reads: thread (tn, rr, lq) sums 16 slabs for 4 floats
    const int tn = t >> 7, rr = (t >> 4) & 7, lq = t & 15;
    const size_t off = (size_t)nt * 4096 + (tm + 2 * tn) * 1024 + (rbase + rr) * 64 + 4 * lq;
    float4 a = {0.f, 0.f, 0.f, 0.f};
#pragma unroll
    for (int s = 0; s < KSPLIT; ++s) {
        const float4 v = *(const float4*)&P[(size_t)s * TILE + off];
        a.x += v.x; a.y += v.y; a.z += v.z; a.w += v.w;
    }
    *(float4*)&a4[tn][rr][4 * lq] = a;
    __syncthreads();
    // write row-major: thread -> (orow, 4-col quad)
    const int orow = q * 16 + (t >> 4);
    const int cquad = t & 15;
    const int lk = (orow >> 2) & 1;
    const int rr2 = ((orow & 3) | (((orow >> 3) & 3) << 2)) - rbase;  // in [0,8)
    float4 o;
    float* op = (float*)&o;
#pragma unroll
    for (int v = 0; v < 4; ++v) {
        const int col = 4 * cquad + v;
        op[v] = a4[col >> 5][rr2][(col & 31) + 32 * lk];
    }
    *(float4*)&Z[(size_t)orow * 4096 + nt * 64 + 4 * cquad] = o;
}

extern "C" void kernel_launch(void* const* d_in, const int* in_sizes, int n_in,
                              void* d_out, int out_size, void* d_ws, size_t ws_size,
                              hipStream_t stream) {
    const float* X     = (const float*)d_in[0];
    const float* F     = (const float*)d_in[1];
    const float* Qs    = (const float*)d_in[2];
    const float* lam   = (const float*)d_in[3];
    const float* gamma = (const float*)d_in[4];
    float* Z = (float*)d_out;

    float* P1 = (float*)d_ws;                    // 16 MB partial slabs (gemm1)
    float* P2 = P1 + (size_t)KSPLIT * TILE;      // 16 MB partial slabs (gemm2)
    float* W  = P2 + (size_t)KSPLIT * TILE;      // 1 MB reduced W (tile order)
    float* Gp = W + TILE;                        // 80 KB: G, G^2, G^4, G^8, G^16
    ushort* Yh = (ushort*)(Gp + 5 * 4096);       // 512 KB Y hi plane (fragment layout)
    ushort* Yl = Yh + TILE;                      // 512 KB Y lo plane
    ushort* Qbf = Yl + TILE;                     // 32 MB bf16 Qs (row-major)

    packq_kernel<<<2048, 256, 0, stream>>>(Qs, Qbf);
    gemm1_kernel<<<64 * KSPLIT + 1, 256, 0, stream>>>(X, Qbf, P1, F, Gp);
    reduce_kernel<<<256, 256, 0, stream>>>(P1, W);
    solve_kernel<<<Ndim / 16, 256, 0, stream>>>(W, Gp, lam, gamma, Yh, Yl);
    gemm2_kernel<<<64 * KSPLIT, 256, 0, stream>>>(Yh, Yl, Qbf, P2);
    reduce2z_kernel<<<256, 256, 0, stream>>>(P2, Z);
}